// Round 1
// baseline (329.719 us; speedup 1.0000x reference)
//
#include <hip/hip_runtime.h>
#include <cstdint>
#include <math.h>

#define S_LEN 2048
#define DM 1024
#define NQKV 1536
#define MROWS 4096   // B * S

typedef __attribute__((ext_vector_type(8))) short short8;
typedef __attribute__((ext_vector_type(4))) float f32x4;

__device__ __forceinline__ short f2bf(float x) {
  union { float f; uint32_t u; } v; v.f = x;
  uint32_t r = (v.u + 0x7fffu + ((v.u >> 16) & 1u)) >> 16;
  return (short)(uint16_t)r;
}

// ---------------- fp32 -> bf16 vectorized convert ----------------
__global__ void f32_to_bf16_vec(const float* __restrict__ in, short* __restrict__ out, int n4) {
  int i = blockIdx.x * blockDim.x + threadIdx.x;
  if (i < n4) {
    float4 v = ((const float4*)in)[i];
    short4 o;
    o.x = f2bf(v.x); o.y = f2bf(v.y); o.z = f2bf(v.z); o.w = f2bf(v.w);
    ((short4*)out)[i] = o;
  }
}

// ---------------- concat Wq|Wk|Wv into bf16 [1024][1536] ----------------
__global__ void build_wcat(const float* __restrict__ Wq, const float* __restrict__ Wk,
                           const float* __restrict__ Wv, short* __restrict__ Wcat) {
  int k = blockIdx.x;  // 0..1023
  for (int c = threadIdx.x; c < NQKV; c += blockDim.x) {
    float v;
    if (c < 1024)      v = Wq[(size_t)k*1024 + c];
    else if (c < 1280) v = Wk[(size_t)k*256 + (c - 1024)];
    else               v = Wv[(size_t)k*256 + (c - 1280)];
    Wcat[(size_t)k*NQKV + c] = f2bf(v);
  }
}

// ---------------- bf16 MFMA GEMM: C[M][N] = A[M][K] * B[K][N] ----------------
// 128x128 tile, BK=64, 256 threads = 4 waves in 2x2, each wave 64x64 (4x4 MFMA frags)
#define BM 128
#define BN 128
#define BKT 64
#define LDT 72   // padded LDS leading dim (bf16 elems); 72*2B=144B -> b128 row reads are 2-way (free)

__global__ __launch_bounds__(256) void gemm_bf16(const short* __restrict__ A,
    const short* __restrict__ B, float* __restrict__ C, int M, int N, int K) {
  __shared__ short As[BM * LDT];   // [BM][BKT]
  __shared__ short Bs[BN * LDT];   // B transposed: [BN][BKT]
  const int tid = threadIdx.x;
  const int wave = tid >> 6, lane = tid & 63;
  const int quad = lane >> 4, l15 = lane & 15;
  const int wm = (wave >> 1) * 64, wn = (wave & 1) * 64;
  const int m0 = blockIdx.y * BM, n0 = blockIdx.x * BN;

  f32x4 acc[4][4] = {};

  for (int k0 = 0; k0 < K; k0 += BKT) {
    __syncthreads();
    // stage A tile: 128 rows x 64 cols, 16B per thread-chunk, coalesced
    #pragma unroll
    for (int i = 0; i < 4; ++i) {
      int chunk = tid + i * 256;                  // 1024 chunks of 8 bf16
      int r = chunk >> 3, c = (chunk & 7) * 8;
      *(uint4*)&As[r*LDT + c] = *(const uint4*)&A[(size_t)(m0 + r)*K + k0 + c];
    }
    // stage B tile transposed: read B[k][n] coalesced, scatter to Bs[n][k] (bank-swizzled)
    #pragma unroll
    for (int i = 0; i < 4; ++i) {
      int chunk = tid + i * 256;                  // 64 k-rows x 16 chunks
      int r = chunk >> 4, c = (chunk & 15) * 8;
      short8 v = *(const short8*)&B[(size_t)(k0 + r)*N + n0 + c];
      int cg = c >> 3;
      #pragma unroll
      for (int j = 0; j < 8; ++j) {
        int jj = (j + cg) & 7;                    // swizzle: spread same-j writes across banks
        Bs[(c + jj)*LDT + r] = v[jj];
      }
    }
    __syncthreads();
    #pragma unroll
    for (int ks = 0; ks < 2; ++ks) {
      short8 af[4], bfr[4];
      #pragma unroll
      for (int mi = 0; mi < 4; ++mi)
        af[mi] = *(const short8*)&As[(wm + mi*16 + l15)*LDT + ks*32 + quad*8];
      #pragma unroll
      for (int ni = 0; ni < 4; ++ni)
        bfr[ni] = *(const short8*)&Bs[(wn + ni*16 + l15)*LDT + ks*32 + quad*8];
      #pragma unroll
      for (int mi = 0; mi < 4; ++mi)
        #pragma unroll
        for (int ni = 0; ni < 4; ++ni)
          acc[mi][ni] = __builtin_amdgcn_mfma_f32_16x16x32_bf16(af[mi], bfr[ni], acc[mi][ni], 0, 0, 0);
    }
  }
  #pragma unroll
  for (int mi = 0; mi < 4; ++mi)
    #pragma unroll
    for (int ni = 0; ni < 4; ++ni)
      #pragma unroll
      for (int r = 0; r < 4; ++r)
        C[(size_t)(m0 + wm + mi*16 + quad*4 + r)*N + (n0 + wn + ni*16 + l15)] = acc[mi][ni][r];
}

// ---------------- RoPE + bf16 pack: QKVf fp32 [4096][1536] -> Qb/Kb/Vb bf16 ----------------
__global__ void rope_kernel(const float* __restrict__ qkv, short* __restrict__ Qb,
                            short* __restrict__ Kb, short* __restrict__ Vb) {
  const int row = blockIdx.x;                 // b*S + s
  const int s = row & (S_LEN - 1);
  const int tid = threadIdx.x;
  const float* rp = qkv + (size_t)row * NQKV;
  // Q: 16 heads x 32 rotation pairs = 512 pairs; 2 per thread
  #pragma unroll
  for (int i = 0; i < 2; ++i) {
    int p = tid + i * 256;
    int hh = p >> 5, j = p & 31;
    float inv = expf(-(float)j * (9.210340371976184f / 32.0f));  // 10000^(-j/32)
    float ang = (float)s * inv;
    float cs = cosf(ang), sn = sinf(ang);
    float x1 = rp[hh*64 + j], x2 = rp[hh*64 + j + 32];
    Qb[(size_t)row*1024 + hh*64 + j]      = f2bf(x1*cs - x2*sn);
    Qb[(size_t)row*1024 + hh*64 + j + 32] = f2bf(x2*cs + x1*sn);
  }
  // K: 4 heads x 32 pairs = 128 pairs
  if (tid < 128) {
    int hh = tid >> 5, j = tid & 31;
    float inv = expf(-(float)j * (9.210340371976184f / 32.0f));
    float ang = (float)s * inv;
    float cs = cosf(ang), sn = sinf(ang);
    float x1 = rp[1024 + hh*64 + j], x2 = rp[1024 + hh*64 + j + 32];
    Kb[(size_t)row*256 + hh*64 + j]      = f2bf(x1*cs - x2*sn);
    Kb[(size_t)row*256 + hh*64 + j + 32] = f2bf(x2*cs + x1*sn);
  }
  // V: straight convert, 256 elems
  Vb[(size_t)row*256 + tid] = f2bf(rp[1280 + tid]);
}

// ---------------- causal GQA flash attention ----------------
// block = (b, h, 64-query tile); 4 waves x 16 query rows; KV tiles of 64
__global__ __launch_bounds__(256) void fattn(const short* __restrict__ Qb,
    const short* __restrict__ Kb, const short* __restrict__ Vb, short* __restrict__ Ctx) {
  __shared__ short Qs[64 * 72];
  __shared__ short Ks[64 * 72];
  __shared__ short Vts[64 * 72];      // V transposed: [d][kv]
  __shared__ short Ps[4][16 * 72];    // per-wave P staging (C-layout -> A-layout)
  const int qt = blockIdx.x & 31;
  const int h  = (blockIdx.x >> 5) & 15;
  const int b  = blockIdx.x >> 9;
  const int q0 = qt * 64;
  const int kvh = h >> 2;             // GQA: 4 query heads per kv head
  const int tid = threadIdx.x, wave = tid >> 6, lane = tid & 63;
  const int quad = lane >> 4, l15 = lane & 15;
  const size_t qbase  = (size_t)b * S_LEN * 1024;
  const size_t kvbase = (size_t)b * S_LEN * 256;

  // stage Q tile [64][64] (rows q0.., cols h*64..)
  #pragma unroll
  for (int i = 0; i < 2; ++i) {
    int chunk = tid + i * 256;
    int r = chunk >> 3, c = (chunk & 7) * 8;
    *(uint4*)&Qs[r*72 + c] = *(const uint4*)&Qb[qbase + (size_t)(q0 + r)*1024 + h*64 + c];
  }
  __syncthreads();
  short8 qf0 = *(const short8*)&Qs[(wave*16 + l15)*72 + quad*8];
  short8 qf1 = *(const short8*)&Qs[(wave*16 + l15)*72 + 32 + quad*8];

  f32x4 o[4] = {};
  float mrow[4] = {-INFINITY, -INFINITY, -INFINITY, -INFINITY};
  float lrow[4] = {0.f, 0.f, 0.f, 0.f};

  for (int kt = 0; kt <= qt; ++kt) {
    const int k0 = kt * 64;
    __syncthreads();
    // stage K [kv][d] and V transposed [d][kv]
    #pragma unroll
    for (int i = 0; i < 2; ++i) {
      int chunk = tid + i * 256;
      int r = chunk >> 3, c = (chunk & 7) * 8;
      *(uint4*)&Ks[r*72 + c] = *(const uint4*)&Kb[kvbase + (size_t)(k0 + r)*256 + kvh*64 + c];
      short8 v = *(const short8*)&Vb[kvbase + (size_t)(k0 + r)*256 + kvh*64 + c];
      int cg = c >> 3;
      #pragma unroll
      for (int j = 0; j < 8; ++j) {
        int jj = (j + cg) & 7;
        Vts[(c + jj)*72 + r] = v[jj];
      }
    }
    __syncthreads();

    // S = Q K^T (16 rows x 64 kv per wave)
    f32x4 sc[4];
    #pragma unroll
    for (int nt = 0; nt < 4; ++nt) {
      short8 b0 = *(const short8*)&Ks[(nt*16 + l15)*72 + quad*8];
      short8 b1 = *(const short8*)&Ks[(nt*16 + l15)*72 + 32 + quad*8];
      f32x4 t = {0.f, 0.f, 0.f, 0.f};
      t = __builtin_amdgcn_mfma_f32_16x16x32_bf16(qf0, b0, t, 0, 0, 0);
      t = __builtin_amdgcn_mfma_f32_16x16x32_bf16(qf1, b1, t, 0, 0, 0);
      sc[nt] = t;
    }
    const bool diag = (kt == qt);
    #pragma unroll
    for (int reg = 0; reg < 4; ++reg) {
      const int qrow = q0 + wave*16 + quad*4 + reg;
      float s0 = sc[0][reg]*0.125f, s1 = sc[1][reg]*0.125f;
      float s2 = sc[2][reg]*0.125f, s3 = sc[3][reg]*0.125f;
      if (diag) {
        if (k0 +  0 + l15 > qrow) s0 = -1e30f;
        if (k0 + 16 + l15 > qrow) s1 = -1e30f;
        if (k0 + 32 + l15 > qrow) s2 = -1e30f;
        if (k0 + 48 + l15 > qrow) s3 = -1e30f;
      }
      float mx = fmaxf(fmaxf(s0, s1), fmaxf(s2, s3));
      #pragma unroll
      for (int off = 1; off < 16; off <<= 1) mx = fmaxf(mx, __shfl_xor(mx, off, 64));
      float mnew = fmaxf(mrow[reg], mx);
      float alpha = __expf(mrow[reg] - mnew);    // exp(-inf)=0 on first tile
      float p0 = __expf(s0 - mnew), p1 = __expf(s1 - mnew);
      float p2 = __expf(s2 - mnew), p3 = __expf(s3 - mnew);
      float sum = p0 + p1 + p2 + p3;
      #pragma unroll
      for (int off = 1; off < 16; off <<= 1) sum += __shfl_xor(sum, off, 64);
      lrow[reg] = lrow[reg]*alpha + sum;
      mrow[reg] = mnew;
      #pragma unroll
      for (int nt = 0; nt < 4; ++nt) o[nt][reg] *= alpha;
      const int prow = (quad*4 + reg)*72;
      Ps[wave][prow +  0 + l15] = f2bf(p0);
      Ps[wave][prow + 16 + l15] = f2bf(p1);
      Ps[wave][prow + 32 + l15] = f2bf(p2);
      Ps[wave][prow + 48 + l15] = f2bf(p3);
    }
    __syncthreads();
    // O += P V  (P re-read in A-layout; V from transposed LDS, contiguous b128)
    short8 af0 = *(const short8*)&Ps[wave][l15*72 + quad*8];
    short8 af1 = *(const short8*)&Ps[wave][l15*72 + 32 + quad*8];
    #pragma unroll
    for (int nt = 0; nt < 4; ++nt) {
      short8 b0 = *(const short8*)&Vts[(nt*16 + l15)*72 + quad*8];
      short8 b1 = *(const short8*)&Vts[(nt*16 + l15)*72 + 32 + quad*8];
      o[nt] = __builtin_amdgcn_mfma_f32_16x16x32_bf16(af0, b0, o[nt], 0, 0, 0);
      o[nt] = __builtin_amdgcn_mfma_f32_16x16x32_bf16(af1, b1, o[nt], 0, 0, 0);
    }
  }
  // epilogue: normalize, write ctx bf16 [b*S+row][h*64+col]
  #pragma unroll
  for (int nt = 0; nt < 4; ++nt)
    #pragma unroll
    for (int reg = 0; reg < 4; ++reg) {
      int row = q0 + wave*16 + quad*4 + reg;
      Ctx[qbase + (size_t)row*1024 + h*64 + nt*16 + l15] = f2bf(o[nt][reg] / lrow[reg]);
    }
}

extern "C" void kernel_launch(void* const* d_in, const int* in_sizes, int n_in,
                              void* d_out, int out_size, void* d_ws, size_t ws_size,
                              hipStream_t stream) {
  const float* x  = (const float*)d_in[0];
  const float* Wq = (const float*)d_in[1];
  const float* Wk = (const float*)d_in[2];
  const float* Wv = (const float*)d_in[3];
  const float* Wo = (const float*)d_in[4];
  float* out = (float*)d_out;

  char* w = (char*)d_ws;
  short* Xb   = (short*)w;  w += (size_t)MROWS * DM * 2;      // x bf16
  short* Wcat = (short*)w;  w += (size_t)DM * NQKV * 2;       // Wq|Wk|Wv bf16
  short* Wob  = (short*)w;  w += (size_t)DM * DM * 2;         // Wo bf16
  float* QKVf = (float*)w;  w += (size_t)MROWS * NQKV * 4;    // qkv fp32
  short* Qbuf = (short*)w;  w += (size_t)MROWS * DM * 2;
  short* Kbuf = (short*)w;  w += (size_t)MROWS * 256 * 2;
  short* Vbuf = (short*)w;  w += (size_t)MROWS * 256 * 2;
  short* Ctx  = (short*)QKVf;   // QKVf dead after rope; reuse for ctx bf16

  f32_to_bf16_vec<<<dim3(4096), dim3(256), 0, stream>>>(x, Xb, MROWS * DM / 4);
  build_wcat<<<dim3(1024), dim3(256), 0, stream>>>(Wq, Wk, Wv, Wcat);
  f32_to_bf16_vec<<<dim3(1024), dim3(256), 0, stream>>>(Wo, Wob, DM * DM / 4);
  gemm_bf16<<<dim3(NQKV / BN, MROWS / BM), dim3(256), 0, stream>>>(Xb, Wcat, QKVf, MROWS, NQKV, DM);
  rope_kernel<<<dim3(MROWS), dim3(256), 0, stream>>>(QKVf, Qbuf, Kbuf, Vbuf);
  fattn<<<dim3(2 * 16 * (S_LEN / 64)), dim3(256), 0, stream>>>(Qbuf, Kbuf, Vbuf, Ctx);
  gemm_bf16<<<dim3(DM / BN, MROWS / BM), dim3(256), 0, stream>>>(Ctx, Wob, out, MROWS, DM, DM);
}

// Round 2
// 249.139 us; speedup vs baseline: 1.3234x; 1.3234x over previous
//
#include <hip/hip_runtime.h>
#include <cstdint>
#include <math.h>

#define S_LEN 2048
#define DM 1024
#define NQKV 1536
#define MROWS 4096   // B * S

typedef __attribute__((ext_vector_type(8))) short short8;
typedef __attribute__((ext_vector_type(4))) float f32x4;

// 0.125 (1/sqrt(64)) * log2(e), folded into Q at RoPE time
#define QFOLD 0.18033688011112042f

__device__ __forceinline__ short f2bf(float x) {
  union { float f; uint32_t u; } v; v.f = x;
  uint32_t r = (v.u + 0x7fffu + ((v.u >> 16) & 1u)) >> 16;
  return (short)(uint16_t)r;
}

// ---------------- fp32 -> bf16 vectorized convert ----------------
__global__ void f32_to_bf16_vec(const float* __restrict__ in, short* __restrict__ out, int n4) {
  int i = blockIdx.x * blockDim.x + threadIdx.x;
  if (i < n4) {
    float4 v = ((const float4*)in)[i];
    short4 o;
    o.x = f2bf(v.x); o.y = f2bf(v.y); o.z = f2bf(v.z); o.w = f2bf(v.w);
    ((short4*)out)[i] = o;
  }
}

// ---------------- fp32 [R][C] -> bf16 transposed dst[c*R + r] ----------------
// 64x64 tiles via LDS; coalesced read and write.
__global__ __launch_bounds__(256) void transpose_f32_bf16(const float* __restrict__ src,
    short* __restrict__ dst, int R, int C) {
  __shared__ short T[64 * 72];
  const int r0 = blockIdx.x * 64, c0 = blockIdx.y * 64;
  const int tid = threadIdx.x;
  #pragma unroll
  for (int i = 0; i < 4; ++i) {
    int chunk = tid + i * 256;               // 1024 float4 chunks
    int r = chunk >> 4, cc = (chunk & 15) * 4;
    float4 v = *(const float4*)&src[(size_t)(r0 + r) * C + c0 + cc];
    T[(cc + 0) * 72 + r] = f2bf(v.x);
    T[(cc + 1) * 72 + r] = f2bf(v.y);
    T[(cc + 2) * 72 + r] = f2bf(v.z);
    T[(cc + 3) * 72 + r] = f2bf(v.w);
  }
  __syncthreads();
  #pragma unroll
  for (int i = 0; i < 2; ++i) {
    int chunk = tid + i * 256;               // 512 short8 chunks
    int rr = chunk >> 3, kk = (chunk & 7) * 8;
    *(uint4*)&dst[(size_t)(c0 + rr) * R + r0 + kk] = *(uint4*)&T[rr * 72 + kk];
  }
}

// ---------------- bf16 MFMA GEMM: C[M][N] = A[M][K] * BT[N][K]^T ----------------
#define BM 128
#define BN 128
#define BKT 64
#define LDT 72   // 144B row stride: 16B-aligned, 2-way bank (free)

__global__ __launch_bounds__(256) void gemm_bf16(const short* __restrict__ A,
    const short* __restrict__ BT, float* __restrict__ C, int M, int N, int K) {
  __shared__ short As[BM * LDT];
  __shared__ short Bs[BN * LDT];
  const int tid = threadIdx.x;
  const int wave = tid >> 6, lane = tid & 63;
  const int quad = lane >> 4, l15 = lane & 15;
  const int wm = (wave >> 1) * 64, wn = (wave & 1) * 64;
  const int m0 = blockIdx.y * BM, n0 = blockIdx.x * BN;

  f32x4 acc[4][4] = {};

  for (int k0 = 0; k0 < K; k0 += BKT) {
    __syncthreads();
    #pragma unroll
    for (int i = 0; i < 4; ++i) {
      int chunk = tid + i * 256;
      int r = chunk >> 3, c = (chunk & 7) * 8;
      *(uint4*)&As[r*LDT + c] = *(const uint4*)&A[(size_t)(m0 + r)*K + k0 + c];
      *(uint4*)&Bs[r*LDT + c] = *(const uint4*)&BT[(size_t)(n0 + r)*K + k0 + c];
    }
    __syncthreads();
    #pragma unroll
    for (int ks = 0; ks < 2; ++ks) {
      short8 af[4], bfr[4];
      #pragma unroll
      for (int mi = 0; mi < 4; ++mi)
        af[mi] = *(const short8*)&As[(wm + mi*16 + l15)*LDT + ks*32 + quad*8];
      #pragma unroll
      for (int ni = 0; ni < 4; ++ni)
        bfr[ni] = *(const short8*)&Bs[(wn + ni*16 + l15)*LDT + ks*32 + quad*8];
      #pragma unroll
      for (int mi = 0; mi < 4; ++mi)
        #pragma unroll
        for (int ni = 0; ni < 4; ++ni)
          acc[mi][ni] = __builtin_amdgcn_mfma_f32_16x16x32_bf16(af[mi], bfr[ni], acc[mi][ni], 0, 0, 0);
    }
  }
  #pragma unroll
  for (int mi = 0; mi < 4; ++mi)
    #pragma unroll
    for (int ni = 0; ni < 4; ++ni)
      #pragma unroll
      for (int r = 0; r < 4; ++r)
        C[(size_t)(m0 + wm + mi*16 + quad*4 + r)*N + (n0 + wn + ni*16 + l15)] = acc[mi][ni][r];
}

// ---------------- RoPE + bf16 pack; Q gets scale*log2e folded in ----------------
__global__ void rope_kernel(const float* __restrict__ qkv, short* __restrict__ Qb,
                            short* __restrict__ Kb, short* __restrict__ Vb) {
  const int row = blockIdx.x;
  const int s = row & (S_LEN - 1);
  const int tid = threadIdx.x;
  const float* rp = qkv + (size_t)row * NQKV;
  #pragma unroll
  for (int i = 0; i < 2; ++i) {
    int p = tid + i * 256;
    int hh = p >> 5, j = p & 31;
    float inv = expf(-(float)j * (9.210340371976184f / 32.0f));
    float ang = (float)s * inv;
    float cs = cosf(ang), sn = sinf(ang);
    float x1 = rp[hh*64 + j], x2 = rp[hh*64 + j + 32];
    Qb[(size_t)row*1024 + hh*64 + j]      = f2bf((x1*cs - x2*sn) * QFOLD);
    Qb[(size_t)row*1024 + hh*64 + j + 32] = f2bf((x2*cs + x1*sn) * QFOLD);
  }
  if (tid < 128) {
    int hh = tid >> 5, j = tid & 31;
    float inv = expf(-(float)j * (9.210340371976184f / 32.0f));
    float ang = (float)s * inv;
    float cs = cosf(ang), sn = sinf(ang);
    float x1 = rp[1024 + hh*64 + j], x2 = rp[1024 + hh*64 + j + 32];
    Kb[(size_t)row*256 + hh*64 + j]      = f2bf(x1*cs - x2*sn);
    Kb[(size_t)row*256 + hh*64 + j + 32] = f2bf(x2*cs + x1*sn);
  }
  Vb[(size_t)row*256 + tid] = f2bf(rp[1280 + tid]);
}

// ---------------- V transpose: Vb[b*S+s][kvh*64+d] -> Vt[(b*4+kvh)*64+d][s] ----------------
__global__ __launch_bounds__(256) void transpose_v(const short* __restrict__ Vb,
                                                   short* __restrict__ Vt) {
  __shared__ short T[64 * 72];
  const int s0 = blockIdx.x * 64;
  const int bh = blockIdx.y;             // b*4 + kvh
  const int b = bh >> 2, kvh = bh & 3;
  const int tid = threadIdx.x;
  #pragma unroll
  for (int i = 0; i < 2; ++i) {
    int chunk = tid + i * 256;
    int r = chunk >> 3, c = (chunk & 7) * 8;   // r: s row, c: d col
    short8 v = *(const short8*)&Vb[(size_t)(b*S_LEN + s0 + r)*256 + kvh*64 + c];
    #pragma unroll
    for (int t = 0; t < 8; ++t) T[(c + t) * 72 + r] = v[t];
  }
  __syncthreads();
  #pragma unroll
  for (int i = 0; i < 2; ++i) {
    int chunk = tid + i * 256;
    int rr = chunk >> 3, kk = (chunk & 7) * 8;  // rr: d, kk: s
    *(uint4*)&Vt[(size_t)(bh*64 + rr)*S_LEN + s0 + kk] = *(uint4*)&T[rr * 72 + kk];
  }
}

// ---------------- causal GQA flash attention v2 ----------------
// grid 256 = (b=2, kvh=4, hh=2, j=16). Block: 2 heads x 2 row-halves (4 waves),
// two 64-row q-tiles (j and 31-j -> 17 KV events each), KV tile = 128 wide.
#define PSTR 136   // 272B row stride: 16B-aligned, 2-way bank

__global__ __launch_bounds__(256, 1) void fattn2(const short* __restrict__ Qb,
    const short* __restrict__ Kb, const short* __restrict__ Vt, short* __restrict__ Ctx) {
  __shared__ short Ks[128 * 72];        // K tile [kv 128][d 64]
  __shared__ short Vts[64 * PSTR];      // V^T tile [d 64][kv 128]
  __shared__ short Ps[4 * 32 * PSTR];   // per-wave P staging [q 32][kv 128]
  const int idx = blockIdx.x;
  const int j   = idx & 15;
  const int hh  = (idx >> 4) & 1;
  const int kvh = (idx >> 5) & 3;
  const int b   = idx >> 7;
  const int tid = threadIdx.x, wave = tid >> 6, lane = tid & 63;
  const int quad = lane >> 4, l15 = lane & 15;
  const int h    = kvh*4 + hh*2 + (wave >> 1);
  const int roff = (wave & 1) * 32;
  const size_t qbase  = (size_t)b * S_LEN * 1024;
  const size_t kbase  = (size_t)b * S_LEN * 256;
  const size_t vtbase = (size_t)(b*4 + kvh) * 64 * S_LEN;
  short* Psw = Ps + wave * 32 * PSTR;

  // staging address pieces (same formulas for prefetch + LDS write)
  for (int half = 0; half < 2; ++half) {
    const int jt = half ? (31 - j) : j;
    const int q0 = jt * 64;
    const int ntiles = (jt >> 1) + 1;

    short8 qf[2][2];
    #pragma unroll
    for (int mi = 0; mi < 2; ++mi)
      #pragma unroll
      for (int ks = 0; ks < 2; ++ks)
        qf[mi][ks] = *(const short8*)&Qb[qbase + (size_t)(q0 + roff + mi*16 + l15)*1024
                                         + h*64 + ks*32 + quad*8];

    f32x4 O[2][4] = {};
    float mm[2][4], ll[2][4];
    #pragma unroll
    for (int mi = 0; mi < 2; ++mi)
      #pragma unroll
      for (int r = 0; r < 4; ++r) { mm[mi][r] = -INFINITY; ll[mi][r] = 0.f; }

    short8 kreg[4], vreg[4];
    // prologue: prefetch tile 0
    #pragma unroll
    for (int i = 0; i < 4; ++i) {
      int chunk = tid + i * 256;
      int kr = chunk >> 3, kc = (chunk & 7) * 8;
      kreg[i] = *(const short8*)&Kb[kbase + (size_t)kr*256 + kvh*64 + kc];
      int vr = chunk >> 4, vc = (chunk & 15) * 8;
      vreg[i] = *(const short8*)&Vt[vtbase + (size_t)vr*S_LEN + vc];
    }

    for (int t = 0; t < ntiles; ++t) {
      const int k0 = t * 128;
      __syncthreads();
      #pragma unroll
      for (int i = 0; i < 4; ++i) {
        int chunk = tid + i * 256;
        int kr = chunk >> 3, kc = (chunk & 7) * 8;
        *(short8*)&Ks[kr*72 + kc] = kreg[i];
        int vr = chunk >> 4, vc = (chunk & 15) * 8;
        *(short8*)&Vts[vr*PSTR + vc] = vreg[i];
      }
      __syncthreads();
      if (t + 1 < ntiles) {
        const int kn = (t + 1) * 128;
        #pragma unroll
        for (int i = 0; i < 4; ++i) {
          int chunk = tid + i * 256;
          int kr = chunk >> 3, kc = (chunk & 7) * 8;
          kreg[i] = *(const short8*)&Kb[kbase + (size_t)(kn + kr)*256 + kvh*64 + kc];
          int vr = chunk >> 4, vc = (chunk & 15) * 8;
          vreg[i] = *(const short8*)&Vt[vtbase + (size_t)vr*S_LEN + kn + vc];
        }
      }

      // S = Q K^T   (32 q-rows x 128 kv per wave)
      f32x4 sc[2][8];
      #pragma unroll
      for (int nt = 0; nt < 8; ++nt) {
        short8 b0 = *(const short8*)&Ks[(nt*16 + l15)*72 + quad*8];
        short8 b1 = *(const short8*)&Ks[(nt*16 + l15)*72 + 32 + quad*8];
        #pragma unroll
        for (int mi = 0; mi < 2; ++mi) {
          f32x4 acc = {0.f, 0.f, 0.f, 0.f};
          acc = __builtin_amdgcn_mfma_f32_16x16x32_bf16(qf[mi][0], b0, acc, 0, 0, 0);
          acc = __builtin_amdgcn_mfma_f32_16x16x32_bf16(qf[mi][1], b1, acc, 0, 0, 0);
          sc[mi][nt] = acc;
        }
      }

      const bool lastt = (t == ntiles - 1);
      #pragma unroll
      for (int mi = 0; mi < 2; ++mi)
        #pragma unroll
        for (int reg = 0; reg < 4; ++reg) {
          const int qrow = q0 + roff + mi*16 + quad*4 + reg;
          float z[8];
          #pragma unroll
          for (int nt = 0; nt < 8; ++nt) z[nt] = sc[mi][nt][reg];
          if (lastt) {
            #pragma unroll
            for (int nt = 0; nt < 8; ++nt)
              if (k0 + nt*16 + l15 > qrow) z[nt] = -1e30f;
          }
          float mx = z[0];
          #pragma unroll
          for (int nt = 1; nt < 8; ++nt) mx = fmaxf(mx, z[nt]);
          #pragma unroll
          for (int off = 1; off < 16; off <<= 1) mx = fmaxf(mx, __shfl_xor(mx, off, 64));
          float mn = fmaxf(mm[mi][reg], mx);
          float alpha = exp2f(mm[mi][reg] - mn);
          float p[8], sum = 0.f;
          #pragma unroll
          for (int nt = 0; nt < 8; ++nt) { p[nt] = exp2f(z[nt] - mn); sum += p[nt]; }
          #pragma unroll
          for (int off = 1; off < 16; off <<= 1) sum += __shfl_xor(sum, off, 64);
          ll[mi][reg] = ll[mi][reg] * alpha + sum;
          mm[mi][reg] = mn;
          #pragma unroll
          for (int d = 0; d < 4; ++d) O[mi][d][reg] *= alpha;
          const int pb = (mi*16 + quad*4 + reg) * PSTR + l15;
          #pragma unroll
          for (int nt = 0; nt < 8; ++nt) Psw[pb + nt*16] = f2bf(p[nt]);
        }

      // O += P V
      #pragma unroll
      for (int ks = 0; ks < 4; ++ks) {
        short8 a0 = *(const short8*)&Psw[(0*16 + l15)*PSTR + ks*32 + quad*8];
        short8 a1 = *(const short8*)&Psw[(1*16 + l15)*PSTR + ks*32 + quad*8];
        #pragma unroll
        for (int d = 0; d < 4; ++d) {
          short8 bv = *(const short8*)&Vts[(d*16 + l15)*PSTR + ks*32 + quad*8];
          O[0][d] = __builtin_amdgcn_mfma_f32_16x16x32_bf16(a0, bv, O[0][d], 0, 0, 0);
          O[1][d] = __builtin_amdgcn_mfma_f32_16x16x32_bf16(a1, bv, O[1][d], 0, 0, 0);
        }
      }
    }

    #pragma unroll
    for (int mi = 0; mi < 2; ++mi)
      #pragma unroll
      for (int d = 0; d < 4; ++d)
        #pragma unroll
        for (int reg = 0; reg < 4; ++reg) {
          int qrow = q0 + roff + mi*16 + quad*4 + reg;
          Ctx[qbase + (size_t)qrow*1024 + h*64 + d*16 + l15] =
              f2bf(O[mi][d][reg] / ll[mi][reg]);
        }
  }
}

extern "C" void kernel_launch(void* const* d_in, const int* in_sizes, int n_in,
                              void* d_out, int out_size, void* d_ws, size_t ws_size,
                              hipStream_t stream) {
  const float* x  = (const float*)d_in[0];
  const float* Wq = (const float*)d_in[1];
  const float* Wk = (const float*)d_in[2];
  const float* Wv = (const float*)d_in[3];
  const float* Wo = (const float*)d_in[4];
  float* out = (float*)d_out;

  char* w = (char*)d_ws;
  short* Xb    = (short*)w;  w += (size_t)MROWS * DM * 2;
  short* WcatT = (short*)w;  w += (size_t)NQKV * DM * 2;     // [1536][1024]
  short* WoT   = (short*)w;  w += (size_t)DM * DM * 2;       // [1024][1024]
  float* QKVf  = (float*)w;  w += (size_t)MROWS * NQKV * 4;
  short* Qbuf  = (short*)w;  w += (size_t)MROWS * DM * 2;
  short* Kbuf  = (short*)w;  w += (size_t)MROWS * 256 * 2;
  short* Vbuf  = (short*)w;  w += (size_t)MROWS * 256 * 2;
  short* Vt    = (short*)w;  w += (size_t)8 * 64 * S_LEN * 2;
  short* Ctx   = (short*)QKVf;   // QKVf dead after rope

  f32_to_bf16_vec<<<dim3(4096), dim3(256), 0, stream>>>(x, Xb, MROWS * DM / 4);
  // weight transposes: dst[c*R + r]
  transpose_f32_bf16<<<dim3(16, 16), dim3(256), 0, stream>>>(Wq, WcatT, 1024, 1024);
  transpose_f32_bf16<<<dim3(16, 4),  dim3(256), 0, stream>>>(Wk, WcatT + (size_t)1024*1024, 1024, 256);
  transpose_f32_bf16<<<dim3(16, 4),  dim3(256), 0, stream>>>(Wv, WcatT + (size_t)1280*1024, 1024, 256);
  transpose_f32_bf16<<<dim3(16, 16), dim3(256), 0, stream>>>(Wo, WoT, 1024, 1024);

  gemm_bf16<<<dim3(NQKV / BN, MROWS / BM), dim3(256), 0, stream>>>(Xb, WcatT, QKVf, MROWS, NQKV, DM);
  rope_kernel<<<dim3(MROWS), dim3(256), 0, stream>>>(QKVf, Qbuf, Kbuf, Vbuf);
  transpose_v<<<dim3(32, 8), dim3(256), 0, stream>>>(Vbuf, Vt);
  fattn2<<<dim3(256), dim3(256), 0, stream>>>(Qbuf, Kbuf, Vt, Ctx);
  gemm_bf16<<<dim3(DM / BN, MROWS / BM), dim3(256), 0, stream>>>(Ctx, WoT, out, MROWS, DM, DM);
}

// Round 4
// 198.101 us; speedup vs baseline: 1.6644x; 1.2576x over previous
//
#include <hip/hip_runtime.h>
#include <hip/hip_bf16.h>
#include <cstdint>
#include <math.h>

#define S_LEN 2048
#define DM 1024
#define NQKV 1536
#define MROWS 4096   // B * S

typedef __attribute__((ext_vector_type(8))) short short8;
typedef __attribute__((ext_vector_type(4))) short short4v;
typedef __attribute__((ext_vector_type(4))) float f32x4;

// compiler-level memory ordering point (same-wave LDS RAW; HW is in-order)
#define MEMBAR() __asm__ __volatile__("" ::: "memory")

// 0.125 (1/sqrt(64)) * log2(e), folded into Q at RoPE time
#define QFOLD 0.18033688011112042f

__device__ __forceinline__ short f2bf(float x) {
  union { float f; uint32_t u; } v; v.f = x;
  uint32_t r = (v.u + 0x7fffu + ((v.u >> 16) & 1u)) >> 16;
  return (short)(uint16_t)r;
}

__device__ __forceinline__ uint32_t pk2(float a, float b) {
  __hip_bfloat162 h = __float22bfloat162_rn(make_float2(a, b));
  union { __hip_bfloat162 h2; uint32_t u; } cv; cv.h2 = h;
  return cv.u;
}

// ---------------- fp32 -> bf16 vectorized convert ----------------
__global__ void f32_to_bf16_vec(const float* __restrict__ in, short* __restrict__ out, int n4) {
  int i = blockIdx.x * blockDim.x + threadIdx.x;
  if (i < n4) {
    float4 v = ((const float4*)in)[i];
    short4 o;
    o.x = f2bf(v.x); o.y = f2bf(v.y); o.z = f2bf(v.z); o.w = f2bf(v.w);
    ((short4*)out)[i] = o;
  }
}

// ---------------- fp32 [R][C] -> bf16 transposed dst[c*R + r] ----------------
__global__ __launch_bounds__(256) void transpose_f32_bf16(const float* __restrict__ src,
    short* __restrict__ dst, int R, int C) {
  __shared__ short T[64 * 72];
  const int r0 = blockIdx.x * 64, c0 = blockIdx.y * 64;
  const int tid = threadIdx.x;
  #pragma unroll
  for (int i = 0; i < 4; ++i) {
    int chunk = tid + i * 256;
    int r = chunk >> 4, cc = (chunk & 15) * 4;
    float4 v = *(const float4*)&src[(size_t)(r0 + r) * C + c0 + cc];
    T[(cc + 0) * 72 + r] = f2bf(v.x);
    T[(cc + 1) * 72 + r] = f2bf(v.y);
    T[(cc + 2) * 72 + r] = f2bf(v.z);
    T[(cc + 3) * 72 + r] = f2bf(v.w);
  }
  __syncthreads();
  #pragma unroll
  for (int i = 0; i < 2; ++i) {
    int chunk = tid + i * 256;
    int rr = chunk >> 3, kk = (chunk & 7) * 8;
    *(uint4*)&dst[(size_t)(c0 + rr) * R + r0 + kk] = *(uint4*)&T[rr * 72 + kk];
  }
}

// ---------------- bf16 MFMA GEMM: C[M][N] = A[M][K] * BT[N][K]^T ----------------
#define BM 128
#define BN 128
#define BKT 64
#define LDT 72

__global__ __launch_bounds__(256) void gemm_bf16(const short* __restrict__ A,
    const short* __restrict__ BT, float* __restrict__ C, int M, int N, int K) {
  __shared__ short As[BM * LDT];
  __shared__ short Bs[BN * LDT];
  const int tid = threadIdx.x;
  const int wave = tid >> 6, lane = tid & 63;
  const int quad = lane >> 4, l15 = lane & 15;
  const int wm = (wave >> 1) * 64, wn = (wave & 1) * 64;
  const int m0 = blockIdx.y * BM, n0 = blockIdx.x * BN;

  f32x4 acc[4][4] = {};

  for (int k0 = 0; k0 < K; k0 += BKT) {
    __syncthreads();
    #pragma unroll
    for (int i = 0; i < 4; ++i) {
      int chunk = tid + i * 256;
      int r = chunk >> 3, c = (chunk & 7) * 8;
      *(uint4*)&As[r*LDT + c] = *(const uint4*)&A[(size_t)(m0 + r)*K + k0 + c];
      *(uint4*)&Bs[r*LDT + c] = *(const uint4*)&BT[(size_t)(n0 + r)*K + k0 + c];
    }
    __syncthreads();
    #pragma unroll
    for (int ks = 0; ks < 2; ++ks) {
      short8 af[4], bfr[4];
      #pragma unroll
      for (int mi = 0; mi < 4; ++mi)
        af[mi] = *(const short8*)&As[(wm + mi*16 + l15)*LDT + ks*32 + quad*8];
      #pragma unroll
      for (int ni = 0; ni < 4; ++ni)
        bfr[ni] = *(const short8*)&Bs[(wn + ni*16 + l15)*LDT + ks*32 + quad*8];
      #pragma unroll
      for (int mi = 0; mi < 4; ++mi)
        #pragma unroll
        for (int ni = 0; ni < 4; ++ni)
          acc[mi][ni] = __builtin_amdgcn_mfma_f32_16x16x32_bf16(af[mi], bfr[ni], acc[mi][ni], 0, 0, 0);
    }
  }
  #pragma unroll
  for (int mi = 0; mi < 4; ++mi)
    #pragma unroll
    for (int ni = 0; ni < 4; ++ni)
      #pragma unroll
      for (int r = 0; r < 4; ++r)
        C[(size_t)(m0 + wm + mi*16 + quad*4 + r)*N + (n0 + wn + ni*16 + l15)] = acc[mi][ni][r];
}

// ---------------- RoPE + bf16 pack; Q gets scale*log2e folded in ----------------
__global__ void rope_kernel(const float* __restrict__ qkv, short* __restrict__ Qb,
                            short* __restrict__ Kb, short* __restrict__ Vb) {
  __shared__ float csn[64];
  const int row = blockIdx.x;
  const int s = row & (S_LEN - 1);
  const int tid = threadIdx.x;
  const float* rp = qkv + (size_t)row * NQKV;
  if (tid < 32) {
    float inv = exp2f(-(float)tid * 0.41524101186092029f);  // log2(10000)/32
    float ang = (float)s * inv;
    csn[tid] = cosf(ang);
    csn[tid + 32] = sinf(ang);
  }
  __syncthreads();
  #pragma unroll
  for (int i = 0; i < 2; ++i) {
    int p = tid + i * 256;
    int hh = p >> 5, j = p & 31;
    float cs = csn[j], sn = csn[j + 32];
    float x1 = rp[hh*64 + j], x2 = rp[hh*64 + j + 32];
    Qb[(size_t)row*1024 + hh*64 + j]      = f2bf((x1*cs - x2*sn) * QFOLD);
    Qb[(size_t)row*1024 + hh*64 + j + 32] = f2bf((x2*cs + x1*sn) * QFOLD);
  }
  if (tid < 128) {
    int hh = tid >> 5, j = tid & 31;
    float cs = csn[j], sn = csn[j + 32];
    float x1 = rp[1024 + hh*64 + j], x2 = rp[1024 + hh*64 + j + 32];
    Kb[(size_t)row*256 + hh*64 + j]      = f2bf(x1*cs - x2*sn);
    Kb[(size_t)row*256 + hh*64 + j + 32] = f2bf(x2*cs + x1*sn);
  }
  Vb[(size_t)row*256 + tid] = f2bf(rp[1280 + tid]);
}

// ---------------- V transpose: Vb[b*S+s][kvh*64+d] -> Vt[(b*4+kvh)*64+d][s] ----------------
__global__ __launch_bounds__(256) void transpose_v(const short* __restrict__ Vb,
                                                   short* __restrict__ Vt) {
  __shared__ short T[64 * 72];
  const int s0 = blockIdx.x * 64;
  const int bh = blockIdx.y;
  const int b = bh >> 2, kvh = bh & 3;
  const int tid = threadIdx.x;
  #pragma unroll
  for (int i = 0; i < 2; ++i) {
    int chunk = tid + i * 256;
    int r = chunk >> 3, c = (chunk & 7) * 8;
    short8 v = *(const short8*)&Vb[(size_t)(b*S_LEN + s0 + r)*256 + kvh*64 + c];
    #pragma unroll
    for (int t = 0; t < 8; ++t) T[(c + t) * 72 + r] = v[t];
  }
  __syncthreads();
  #pragma unroll
  for (int i = 0; i < 2; ++i) {
    int chunk = tid + i * 256;
    int rr = chunk >> 3, kk = (chunk & 7) * 8;
    *(uint4*)&Vt[(size_t)(bh*64 + rr)*S_LEN + s0 + kk] = *(uint4*)&T[rr * 72 + kk];
  }
}

// ---------------- causal GQA flash attention v3 (fixed LDS ordering) ----------------
// grid 512: idx&255 -> (b,kvh,hh,j); idx>=256 -> complementary tile 31-j.
// Block: 2 heads x 2 row-halves (4 waves), one 64-row q-tile, KV tile = 128.
// Softmax on S^T = K*Q^T (q per-lane in registers): 2 shuffles/row-group.
#define PSTR 136

__global__ __launch_bounds__(256, 2) void fattn3(const short* __restrict__ Qb,
    const short* __restrict__ Kb, const short* __restrict__ Vt, short* __restrict__ Ctx) {
  __shared__ short Ks[128 * 72];        // K tile [kv 128][d 64]
  __shared__ short Vts[64 * PSTR];      // V^T tile [d 64][kv 128]
  __shared__ short Ps[4 * 32 * PSTR];   // per-wave P [q 32][kv 128]
  __shared__ float Asc[4 * 32];         // per-wave alpha / 1/l broadcast patch
  const int idx = blockIdx.x;
  const int pair = idx & 255;
  const int j   = pair & 15;
  const int hh  = (pair >> 4) & 1;
  const int kvh = (pair >> 5) & 3;
  const int b   = pair >> 7;
  const int jt  = (idx < 256) ? j : (31 - j);
  const int q0  = jt * 64;
  const int ntiles = (jt >> 1) + 1;
  const int tid = threadIdx.x, wave = tid >> 6, lane = tid & 63;
  const int quad = lane >> 4, l15 = lane & 15;
  const int h    = kvh*4 + hh*2 + (wave >> 1);
  const int roff = (wave & 1) * 32;
  const size_t qbase  = (size_t)b * S_LEN * 1024;
  const size_t kbase  = (size_t)b * S_LEN * 256;
  const size_t vtbase = (size_t)(b*4 + kvh) * 64 * S_LEN;
  short* Psw = Ps + wave * 32 * PSTR;
  float* AscW = Asc + wave * 32;

  // Q B-frags (for St = K * Q^T): B[k=d][n=q] == Q[q=l15][d=quad*8+..], direct global
  short8 qf[2][2];
  #pragma unroll
  for (int mi = 0; mi < 2; ++mi)
    #pragma unroll
    for (int ks = 0; ks < 2; ++ks)
      qf[mi][ks] = *(const short8*)&Qb[qbase + (size_t)(q0 + roff + mi*16 + l15)*1024
                                       + h*64 + ks*32 + quad*8];

  f32x4 O[2][4] = {};
  float mm[2] = {-INFINITY, -INFINITY};
  float ll[2] = {0.f, 0.f};

  short8 kreg[4], vreg[4];
  #pragma unroll
  for (int i = 0; i < 4; ++i) {
    int chunk = tid + i * 256;
    int kr = chunk >> 3, kc = (chunk & 7) * 8;
    kreg[i] = *(const short8*)&Kb[kbase + (size_t)kr*256 + kvh*64 + kc];
    int vr = chunk >> 4, vc = (chunk & 15) * 8;
    vreg[i] = *(const short8*)&Vt[vtbase + (size_t)vr*S_LEN + vc];
  }

  for (int t = 0; t < ntiles; ++t) {
    const int k0 = t * 128;
    __syncthreads();
    #pragma unroll
    for (int i = 0; i < 4; ++i) {
      int chunk = tid + i * 256;
      int kr = chunk >> 3, kc = (chunk & 7) * 8;
      *(short8*)&Ks[kr*72 + kc] = kreg[i];
      int vr = chunk >> 4, vc = (chunk & 15) * 8;
      *(short8*)&Vts[vr*PSTR + vc] = vreg[i];
    }
    __syncthreads();
    if (t + 1 < ntiles) {
      const int kn = (t + 1) * 128;
      #pragma unroll
      for (int i = 0; i < 4; ++i) {
        int chunk = tid + i * 256;
        int kr = chunk >> 3, kc = (chunk & 7) * 8;
        kreg[i] = *(const short8*)&Kb[kbase + (size_t)(kn + kr)*256 + kvh*64 + kc];
        int vr = chunk >> 4, vc = (chunk & 15) * 8;
        vreg[i] = *(const short8*)&Vt[vtbase + (size_t)vr*S_LEN + kn + vc];
      }
    }

    // St = K Q^T : element (kv = k0+nt*16+quad*4+reg, q = q0+roff+mi*16+l15)
    f32x4 sc[2][8];
    #pragma unroll
    for (int nt = 0; nt < 8; ++nt) {
      short8 k0f = *(const short8*)&Ks[(nt*16 + l15)*72 + quad*8];
      short8 k1f = *(const short8*)&Ks[(nt*16 + l15)*72 + 32 + quad*8];
      #pragma unroll
      for (int mi = 0; mi < 2; ++mi) {
        f32x4 acc = {0.f, 0.f, 0.f, 0.f};
        acc = __builtin_amdgcn_mfma_f32_16x16x32_bf16(k0f, qf[mi][0], acc, 0, 0, 0);
        acc = __builtin_amdgcn_mfma_f32_16x16x32_bf16(k1f, qf[mi][1], acc, 0, 0, 0);
        sc[mi][nt] = acc;
      }
    }

    const bool lastt = (t == ntiles - 1);
    float al[2];
    #pragma unroll
    for (int mi = 0; mi < 2; ++mi) {
      const int qrow = q0 + roff + mi*16 + l15;
      if (lastt) {
        #pragma unroll
        for (int nt = 0; nt < 8; ++nt)
          #pragma unroll
          for (int r = 0; r < 4; ++r)
            if (k0 + nt*16 + quad*4 + r > qrow) sc[mi][nt][r] = -1e30f;
      }
      float mx = -1e30f;
      #pragma unroll
      for (int nt = 0; nt < 8; ++nt) {
        float a = fmaxf(sc[mi][nt][0], sc[mi][nt][1]);
        float c = fmaxf(sc[mi][nt][2], sc[mi][nt][3]);
        mx = fmaxf(mx, fmaxf(a, c));
      }
      mx = fmaxf(mx, __shfl_xor(mx, 16, 64));
      mx = fmaxf(mx, __shfl_xor(mx, 32, 64));
      float mn = fmaxf(mm[mi], mx);
      float alpha = exp2f(mm[mi] - mn);
      float sum = 0.f;
      #pragma unroll
      for (int nt = 0; nt < 8; ++nt) {
        float p0 = exp2f(sc[mi][nt][0] - mn);
        float p1 = exp2f(sc[mi][nt][1] - mn);
        float p2 = exp2f(sc[mi][nt][2] - mn);
        float p3 = exp2f(sc[mi][nt][3] - mn);
        sum += (p0 + p1) + (p2 + p3);
        union { uint2 u; short4v s; } pkc;
        pkc.u.x = pk2(p0, p1); pkc.u.y = pk2(p2, p3);
        *(short4v*)&Psw[(mi*16 + l15)*PSTR + nt*16 + quad*4] = pkc.s;
      }
      sum += __shfl_xor(sum, 16, 64);
      sum += __shfl_xor(sum, 32, 64);
      ll[mi] = ll[mi]*alpha + sum;
      mm[mi] = mn;
      al[mi] = alpha;
    }
    // broadcast alpha from q=l15 layout to C-layout rows q=quad*4+reg
    if (quad < 2) AscW[quad*16 + l15] = al[quad];
    MEMBAR();   // order LDS writes (P, alpha) before the reads below
    float av0[4], av1[4];
    #pragma unroll
    for (int r = 0; r < 4; ++r) {
      av0[r] = AscW[quad*4 + r];
      av1[r] = AscW[16 + quad*4 + r];
    }
    #pragma unroll
    for (int d = 0; d < 4; ++d)
      #pragma unroll
      for (int r = 0; r < 4; ++r) {
        O[0][d][r] *= av0[r];
        O[1][d][r] *= av1[r];
      }

    // O += P V
    #pragma unroll
    for (int ks = 0; ks < 4; ++ks) {
      short8 a0 = *(const short8*)&Psw[(0*16 + l15)*PSTR + ks*32 + quad*8];
      short8 a1 = *(const short8*)&Psw[(1*16 + l15)*PSTR + ks*32 + quad*8];
      #pragma unroll
      for (int d = 0; d < 4; ++d) {
        short8 bv = *(const short8*)&Vts[(d*16 + l15)*PSTR + ks*32 + quad*8];
        O[0][d] = __builtin_amdgcn_mfma_f32_16x16x32_bf16(a0, bv, O[0][d], 0, 0, 0);
        O[1][d] = __builtin_amdgcn_mfma_f32_16x16x32_bf16(a1, bv, O[1][d], 0, 0, 0);
      }
    }
  }

  // epilogue: broadcast 1/l, write ctx bf16
  if (quad < 2) AscW[quad*16 + l15] = 1.0f / ll[quad];
  MEMBAR();
  float lv0[4], lv1[4];
  #pragma unroll
  for (int r = 0; r < 4; ++r) {
    lv0[r] = AscW[quad*4 + r];
    lv1[r] = AscW[16 + quad*4 + r];
  }
  #pragma unroll
  for (int d = 0; d < 4; ++d)
    #pragma unroll
    for (int r = 0; r < 4; ++r) {
      int qrow0 = q0 + roff + quad*4 + r;
      Ctx[qbase + (size_t)qrow0*1024 + h*64 + d*16 + l15] = f2bf(O[0][d][r] * lv0[r]);
      int qrow1 = q0 + roff + 16 + quad*4 + r;
      Ctx[qbase + (size_t)qrow1*1024 + h*64 + d*16 + l15] = f2bf(O[1][d][r] * lv1[r]);
    }
}

extern "C" void kernel_launch(void* const* d_in, const int* in_sizes, int n_in,
                              void* d_out, int out_size, void* d_ws, size_t ws_size,
                              hipStream_t stream) {
  const float* x  = (const float*)d_in[0];
  const float* Wq = (const float*)d_in[1];
  const float* Wk = (const float*)d_in[2];
  const float* Wv = (const float*)d_in[3];
  const float* Wo = (const float*)d_in[4];
  float* out = (float*)d_out;

  char* w = (char*)d_ws;
  short* Xb    = (short*)w;  w += (size_t)MROWS * DM * 2;
  short* WcatT = (short*)w;  w += (size_t)NQKV * DM * 2;
  short* WoT   = (short*)w;  w += (size_t)DM * DM * 2;
  float* QKVf  = (float*)w;  w += (size_t)MROWS * NQKV * 4;
  short* Qbuf  = (short*)w;  w += (size_t)MROWS * DM * 2;
  short* Kbuf  = (short*)w;  w += (size_t)MROWS * 256 * 2;
  short* Vbuf  = (short*)w;  w += (size_t)MROWS * 256 * 2;
  short* Vt    = (short*)w;  w += (size_t)8 * 64 * S_LEN * 2;
  short* Ctx   = (short*)QKVf;   // QKVf dead after rope

  f32_to_bf16_vec<<<dim3(4096), dim3(256), 0, stream>>>(x, Xb, MROWS * DM / 4);
  transpose_f32_bf16<<<dim3(16, 16), dim3(256), 0, stream>>>(Wq, WcatT, 1024, 1024);
  transpose_f32_bf16<<<dim3(16, 4),  dim3(256), 0, stream>>>(Wk, WcatT + (size_t)1024*1024, 1024, 256);
  transpose_f32_bf16<<<dim3(16, 4),  dim3(256), 0, stream>>>(Wv, WcatT + (size_t)1280*1024, 1024, 256);
  transpose_f32_bf16<<<dim3(16, 16), dim3(256), 0, stream>>>(Wo, WoT, 1024, 1024);

  gemm_bf16<<<dim3(NQKV / BN, MROWS / BM), dim3(256), 0, stream>>>(Xb, WcatT, QKVf, MROWS, NQKV, DM);
  rope_kernel<<<dim3(MROWS), dim3(256), 0, stream>>>(QKVf, Qbuf, Kbuf, Vbuf);
  transpose_v<<<dim3(32, 8), dim3(256), 0, stream>>>(Vbuf, Vt);
  fattn3<<<dim3(512), dim3(256), 0, stream>>>(Qbuf, Kbuf, Vt, Ctx);
  gemm_bf16<<<dim3(DM / BN, MROWS / BM), dim3(256), 0, stream>>>(Ctx, WoT, out, MROWS, DM, DM);
}